// Round 10
// baseline (61.348 us; speedup 1.0000x reference)
//
#include <hip/hip_runtime.h>

// K[b,i,j] = exp(-|xi-xj|^2/2), points [4,4096,64] fp32, out [4,4096,4096] fp32.
// Single bf16 MFMA Gram GEMM, fp32->bf16 conversion fused into staging.
// Points pre-scaled by sqrt(log2(e)) before bf16 rounding, so
// acc - na' - nb' = log2e * (-d2_hat/2) and the epilogue is a raw exp2.
// Norms (fp32, from the SAME scaled bf16 values) are folded into the
// accumulator INIT (MFMA C-in), so the epilogue is exp2 + store only:
// no sub, no clamp, no diag branch (diag error ~1e-4 << 2e-2 threshold;
// off-diag v <= -10 so no clamp needed; v_exp_f32 underflows to 0 like fp32 ref).
// Geometry: 128x128 tile, 256 thr (4 waves 2x2), 33 KB LDS -> 4 blocks/CU.
// NOTE: nontemporal stores regressed; 64x256 / zero-LDS / persistent-4-tile
// all regressed; stage->barrier->MFMA->store at 4 blocks/CU is the optimum.

#define NPTS 4096
#define DDIM 64
#define BT 128
#define NTB (NPTS / BT)   // 32
#define SQRT_LOG2E 1.20112240878f   // sqrt(1.44269504089)

typedef __attribute__((ext_vector_type(8))) short bf16x8;
typedef __attribute__((ext_vector_type(4))) float f32x4;

__device__ __forceinline__ ushort bf16_rne(float x) {
    union { float f; unsigned u; } v; v.f = x;
    unsigned r = v.u + 0x7fffu + ((v.u >> 16) & 1u);
    return (ushort)(r >> 16);
}
__device__ __forceinline__ float bf16_f(ushort b) {
    union { float f; unsigned u; } v; v.u = ((unsigned)b) << 16;
    return v.f;
}

__global__ __launch_bounds__(256)
void KernelDistance_74972949119307_kernel(const float* __restrict__ pts,
                                          float* __restrict__ out) {
    // 16 KB + 16 KB tiles, chunk-XOR swizzle c' = c ^ (row&7); + 1 KB norms.
    __shared__ ushort Ah[BT * DDIM];
    __shared__ ushort Bh[BT * DDIM];
    __shared__ float na_s[BT];
    __shared__ float nb_s[BT];

    const int bx = blockIdx.x, by = blockIdx.y, bz = blockIdx.z;
    const int tid = threadIdx.x;

    // ---- Stage A/B tiles: fp32 -> scale -> bf16 RNE -> swizzled LDS; norms from bf16 ----
#pragma unroll
    for (int tile = 0; tile < 2; ++tile) {
        const size_t rowbase = ((size_t)bz * NPTS + (size_t)(tile ? bx : by) * BT) * DDIM;
        ushort* L = tile ? Bh : Ah;
        float* ns = tile ? nb_s : na_s;
#pragma unroll
        for (int k = 0; k < 4; ++k) {
            const int f = k * 256 + tid;       // 16B chunk index [0,1024)
            const int row = f >> 3;            // [0,128)
            const int c = f & 7;               // logical chunk in row
            const float4* g4 = (const float4*)(pts + rowbase) + (size_t)f * 2;
            const float4 v0 = g4[0], v1 = g4[1];
            const float fv[8] = {v0.x, v0.y, v0.z, v0.w, v1.x, v1.y, v1.z, v1.w};
            union { ushort us[8]; bf16x8 v; } H;
            float s = 0.f;
#pragma unroll
            for (int j = 0; j < 8; ++j) {
                H.us[j] = bf16_rne(fv[j] * SQRT_LOG2E);
                const float x = bf16_f(H.us[j]);
                s += x * x;
            }
            s += __shfl_xor(s, 1);
            s += __shfl_xor(s, 2);
            s += __shfl_xor(s, 4);
            *(bf16x8*)&L[row * DDIM + (c ^ (row & 7)) * 8] = H.v;
            if (c == 0) ns[row] = 0.5f * s;     // na' = 0.5*log2e*|x_hat|^2
        }
    }
    __syncthreads();

    // ---- 4 waves 2x2, each 64x64 = 4x4 tiles of 16x16, K=64 in two steps ----
    const int lane = tid & 63;
    const int wid = tid >> 6;
    const int wm = (wid >> 1) * 64;
    const int wn = (wid & 1) * 64;
    const int ml = lane & 15;
    const int g = lane >> 4;

    // ---- Fold norms into accumulator init: acc = -(na'[row] + nb'[col]) ----
    // C/D layout: row = wm + mt*16 + g*4 + reg, col = wn + nt*16 + ml.
    f32x4 acc[4][4];
    {
        float nbn[4];
#pragma unroll
        for (int nt = 0; nt < 4; ++nt) nbn[nt] = -nb_s[wn + nt * 16 + ml];
#pragma unroll
        for (int mt = 0; mt < 4; ++mt) {
            const f32x4 nav = *(const f32x4*)&na_s[wm + mt * 16 + g * 4];
#pragma unroll
            for (int nt = 0; nt < 4; ++nt) {
#pragma unroll
                for (int reg = 0; reg < 4; ++reg)
                    acc[mt][nt][reg] = nbn[nt] - nav[reg];
            }
        }
    }

#pragma unroll
    for (int s = 0; s < 2; ++s) {
        bf16x8 a[4], b[4];
#pragma unroll
        for (int mt = 0; mt < 4; ++mt) {
            const int row = wm + mt * 16 + ml;
            const int c = (4 * s + g) ^ (row & 7);
            a[mt] = *(const bf16x8*)&Ah[row * DDIM + c * 8];
        }
#pragma unroll
        for (int nt = 0; nt < 4; ++nt) {
            const int row = wn + nt * 16 + ml;
            const int c = (4 * s + g) ^ (row & 7);
            b[nt] = *(const bf16x8*)&Bh[row * DDIM + c * 8];
        }
#pragma unroll
        for (int mt = 0; mt < 4; ++mt)
#pragma unroll
            for (int nt = 0; nt < 4; ++nt)
                acc[mt][nt] = __builtin_amdgcn_mfma_f32_16x16x32_bf16(a[mt], b[nt], acc[mt][nt], 0, 0, 0);
    }

    // ---- Epilogue: K = exp2(acc) (acc already = log2e*(-d2/2)); store ----
    float* outB = out + ((size_t)bz * NPTS + (size_t)by * BT) * NPTS + (size_t)bx * BT;

#pragma unroll
    for (int mt = 0; mt < 4; ++mt) {
#pragma unroll
        for (int reg = 0; reg < 4; ++reg) {
            const int row = wm + mt * 16 + g * 4 + reg;
            float* orow = outB + (size_t)row * NPTS;
#pragma unroll
            for (int nt = 0; nt < 4; ++nt) {
                const int col = wn + nt * 16 + ml;
                orow[col] = __builtin_amdgcn_exp2f(acc[mt][nt][reg]);
            }
        }
    }
}

extern "C" void kernel_launch(void* const* d_in, const int* in_sizes, int n_in,
                              void* d_out, int out_size, void* d_ws, size_t ws_size,
                              hipStream_t stream) {
    const float* pts = (const float*)d_in[0];
    float* out = (float*)d_out;
    dim3 grid(NTB, NTB, 4);
    KernelDistance_74972949119307_kernel<<<grid, 256, 0, stream>>>(pts, out);
}

// Round 11
// 53.750 us; speedup vs baseline: 1.1414x; 1.1414x over previous
//
#include <hip/hip_runtime.h>

// K[b,i,j] = exp(-|xi-xj|^2/2), points [4,4096,64] fp32, out [4,4096,4096] fp32.
// Single bf16 MFMA Gram GEMM, fp32->bf16 (RNE) conversion fused into staging.
// Norms computed from the SAME bf16 values as the GEMM operands, so
// inner - na - nb == -0.5*|hi(x)-hi(y)|^2 algebraically; diagonal forced to 1.
// STREAMED EPILOGUE: B fragments preloaded to registers; per mt-slab the 8
// MFMAs complete and that slab's exp+stores issue immediately, spreading
// stores across the compute phase (R9 bunched all 64 stores at block end).
// Geometry: 128x128 tile, 256 thr (4 waves 2x2), 33 KB LDS -> 4 blocks/CU.
// NOTE: nontemporal stores regressed; 64x256 / zero-LDS / persistent-4-tile /
// norm-folded-acc-init all regressed. Keep cached scalar stores, R9 math.

#define NPTS 4096
#define DDIM 64
#define BT 128
#define NTB (NPTS / BT)   // 32

typedef __attribute__((ext_vector_type(8))) short bf16x8;
typedef __attribute__((ext_vector_type(4))) float f32x4;

__device__ __forceinline__ ushort bf16_rne(float x) {
    union { float f; unsigned u; } v; v.f = x;
    unsigned r = v.u + 0x7fffu + ((v.u >> 16) & 1u);
    return (ushort)(r >> 16);
}
__device__ __forceinline__ float bf16_f(ushort b) {
    union { float f; unsigned u; } v; v.u = ((unsigned)b) << 16;
    return v.f;
}

__global__ __launch_bounds__(256)
void KernelDistance_74972949119307_kernel(const float* __restrict__ pts,
                                          float* __restrict__ out) {
    // 16 KB + 16 KB tiles, chunk-XOR swizzle c' = c ^ (row&7); + 1 KB norms.
    __shared__ ushort Ah[BT * DDIM];
    __shared__ ushort Bh[BT * DDIM];
    __shared__ float na_s[BT];
    __shared__ float nb_s[BT];

    const int bx = blockIdx.x, by = blockIdx.y, bz = blockIdx.z;
    const int tid = threadIdx.x;

    // ---- Stage A/B tiles: fp32 load -> bf16 RNE -> swizzled LDS; norms from bf16 ----
#pragma unroll
    for (int tile = 0; tile < 2; ++tile) {
        const size_t rowbase = ((size_t)bz * NPTS + (size_t)(tile ? bx : by) * BT) * DDIM;
        ushort* L = tile ? Bh : Ah;
        float* ns = tile ? nb_s : na_s;
#pragma unroll
        for (int k = 0; k < 4; ++k) {
            const int f = k * 256 + tid;       // 16B chunk index [0,1024)
            const int row = f >> 3;            // [0,128)
            const int c = f & 7;               // logical chunk in row
            const float4* g4 = (const float4*)(pts + rowbase) + (size_t)f * 2;
            const float4 v0 = g4[0], v1 = g4[1];
            const float fv[8] = {v0.x, v0.y, v0.z, v0.w, v1.x, v1.y, v1.z, v1.w};
            union { ushort us[8]; bf16x8 v; } H;
            float s = 0.f;
#pragma unroll
            for (int j = 0; j < 8; ++j) {
                H.us[j] = bf16_rne(fv[j]);
                const float x = bf16_f(H.us[j]);
                s += x * x;
            }
            s += __shfl_xor(s, 1);
            s += __shfl_xor(s, 2);
            s += __shfl_xor(s, 4);
            *(bf16x8*)&L[row * DDIM + (c ^ (row & 7)) * 8] = H.v;
            if (c == 0) ns[row] = 0.5f * s;
        }
    }
    __syncthreads();

    // ---- 4 waves 2x2; B fragments (both K-steps) preloaded to registers ----
    const int lane = tid & 63;
    const int wid = tid >> 6;
    const int wm = (wid >> 1) * 64;
    const int wn = (wid & 1) * 64;
    const int ml = lane & 15;
    const int g = lane >> 4;

    bf16x8 bfrag[2][4];
#pragma unroll
    for (int s = 0; s < 2; ++s)
#pragma unroll
        for (int nt = 0; nt < 4; ++nt) {
            const int row = wn + nt * 16 + ml;
            const int c = (4 * s + g) ^ (row & 7);
            bfrag[s][nt] = *(const bf16x8*)&Bh[row * DDIM + c * 8];
        }

    float nbv[4];
#pragma unroll
    for (int nt = 0; nt < 4; ++nt) nbv[nt] = nb_s[wn + nt * 16 + ml];

    float* outB = out + ((size_t)bz * NPTS + (size_t)by * BT) * NPTS + (size_t)bx * BT;
    const bool diagblk = (bx == by);

    // ---- Streamed per-mt: 8 MFMAs then that slab's exp+stores immediately ----
#pragma unroll
    for (int mt = 0; mt < 4; ++mt) {
        f32x4 acc[4];
#pragma unroll
        for (int nt = 0; nt < 4; ++nt) acc[nt] = (f32x4){0.f, 0.f, 0.f, 0.f};

#pragma unroll
        for (int s = 0; s < 2; ++s) {
            const int arow = wm + mt * 16 + ml;
            const int c = (4 * s + g) ^ (arow & 7);
            const bf16x8 a = *(const bf16x8*)&Ah[arow * DDIM + c * 8];
#pragma unroll
            for (int nt = 0; nt < 4; ++nt)
                acc[nt] = __builtin_amdgcn_mfma_f32_16x16x32_bf16(a, bfrag[s][nt], acc[nt], 0, 0, 0);
        }

        const f32x4 nav = *(const f32x4*)&na_s[wm + mt * 16 + g * 4];
#pragma unroll
        for (int reg = 0; reg < 4; ++reg) {
            const int row = wm + mt * 16 + g * 4 + reg;   // C/D: row=(lane>>4)*4+reg
            float* orow = outB + (size_t)row * NPTS;
#pragma unroll
            for (int nt = 0; nt < 4; ++nt) {
                const int col = wn + nt * 16 + ml;        // C/D: col=lane&15
                const float v = acc[nt][reg] - nav[reg] - nbv[nt];
                float kv = __expf(fminf(v, 0.f));
                if (diagblk && row == col) kv = 1.0f;
                orow[col] = kv;
            }
        }
    }
}

extern "C" void kernel_launch(void* const* d_in, const int* in_sizes, int n_in,
                              void* d_out, int out_size, void* d_ws, size_t ws_size,
                              hipStream_t stream) {
    const float* pts = (const float*)d_in[0];
    float* out = (float*)d_out;
    dim3 grid(NTB, NTB, 4);
    KernelDistance_74972949119307_kernel<<<grid, 256, 0, stream>>>(pts, out);
}